// Round 6
// baseline (152.807 us; speedup 1.0000x reference)
//
#include <hip/hip_runtime.h>

#define BATCH 2
#define H 512
#define W 512
#define CS 21
#define CI 3
#define P 128            // output pixels per block
#define TPB 256
#define SLOTS (P + 2)    // 130 slots incl. halo
#define STRIDE 24        // 96 B/slot = 6 float4 chunks -> lane-contiguous LDS
#define GSZ (3 * SLOTS * CI)   // 1170 guide floats

__device__ __forceinline__ void fma4(float4& a, const float4 v, const float w) {
    a.x = fmaf(v.x, w, a.x);
    a.y = fmaf(v.y, w, a.y);
    a.z = fmaf(v.z, w, a.z);
    a.w = fmaf(v.w, w, a.w);
}

// LDS: s_src = 3 rows x 130 slots x 24 floats (37.4 KB). Tap reads are
// lane-contiguous 16B chunks (addr = item*16 + const) -> conflict-free b128.
// Words 21..23 of each slot are never written; q=5 taps read them into
// discarded accumulator lanes (benign garbage).
__global__ __launch_bounds__(TPB, 3) void jbu_kernel(
    const float* __restrict__ src, const float* __restrict__ im,
    float* __restrict__ out)
{
    __shared__ __align__(16) float s_src[3 * SLOTS * STRIDE];  // 37,440 B
    __shared__ __align__(16) float s_w[P * 12];                // 6,144 B

    const int t = threadIdx.x;

    // XCD-aware swizzle: XCD (f&7) owns a contiguous 64-row band.
    const int f   = blockIdx.x;          // 0..4095
    const int xcd = f & 7;
    const int g   = f >> 3;              // 0..511
    const int y   = (xcd << 6) | (g & 63);
    const int rem = g >> 6;              // 0..7
    const int x0  = (rem & 3) << 7;      // segment * 128
    const int b   = rem >> 2;

    const int ry0 = (y == 0)     ? 1     : y - 1;
    const int ry2 = (y == H - 1) ? H - 2 : y + 1;

    // ---- stage guide tile into s_w area (linear [r][slot][ch]) ----
    {
        const float* imb = im + (size_t)b * (H * W * CI);
        for (int i = t; i < GSZ; i += TPB) {
            int r    = i / (SLOTS * CI);
            int remi = i - r * (SLOTS * CI);
            int slot = remi / CI;
            int ch   = remi - slot * CI;
            int ry   = (r == 0) ? ry0 : ((r == 1) ? y : ry2);
            int gx   = x0 + slot - 1;
            gx = (gx < 0) ? 1 : ((gx >= W) ? W - 2 : gx);
            s_w[i] = imb[(ry * W + gx) * CI + ch];
        }
    }

    // ---- stage 3 src rows: contiguous dwordx4, LDS writes at i*16 B ----
    {
        for (int i = t; i < 3 * SLOTS * 6; i += TPB) {   // 2340 items
            int r    = i / (SLOTS * 6);
            int remi = i - r * (SLOTS * 6);
            int slot = remi / 6;
            int q    = remi - slot * 6;
            int ry   = (r == 0) ? ry0 : ((r == 1) ? y : ry2);
            int gx   = x0 + slot - 1;
            gx = (gx < 0) ? 1 : ((gx >= W) ? W - 2 : gx);
            const float* srow = src + ((size_t)(b * H + ry) * W + gx) * CS;
            float* dst = &s_src[(r * SLOTS + slot) * STRIDE];
            if (q < 5) {
                *(float4*)(dst + (q << 2)) = *(const float4*)(srow + (q << 2));
            } else {
                dst[20] = srow[20];           // ch 20 scalar
            }
        }
    }
    __syncthreads();

    // ---- weights in registers (t<128), normalized ----
    float4 wa, wb;
    float  w8n;
    if (t < P) {
        const float w1k[9] = {0.36787944f, 0.60653066f, 0.36787944f,
                              0.60653066f, 1.0f,        0.60653066f,
                              0.36787944f, 0.60653066f, 0.36787944f};
        const int cbase = (SLOTS + t + 1) * CI;
        const float c0 = s_w[cbase + 0];
        const float c1 = s_w[cbase + 1];
        const float c2 = s_w[cbase + 2];
        float wv[9];
        float den = 0.f;
        #pragma unroll
        for (int k = 0; k < 9; ++k) {
            const int dy = k / 3, dx = k % 3;
            const int idx = (dy * SLOTS + t + dx) * CI;
            float d0 = s_w[idx + 0] - c0;
            float d1 = s_w[idx + 1] - c1;
            float d2 = s_w[idx + 2] - c2;
            float w = __expf(-8.0f * (d0 * d0 + d1 * d1 + d2 * d2)) * w1k[k];
            wv[k] = w;
            den += w;
        }
        const float inv = 1.0f / den;
        wa  = make_float4(wv[0] * inv, wv[1] * inv, wv[2] * inv, wv[3] * inv);
        wb  = make_float4(wv[4] * inv, wv[5] * inv, wv[6] * inv, wv[7] * inv);
        w8n = wv[8] * inv;
    }
    __syncthreads();   // guide-tile reads done before overwrite

    if (t < P) {
        *(float4*)&s_w[t * 12 + 0] = wa;
        *(float4*)&s_w[t * 12 + 4] = wb;
        s_w[t * 12 + 8] = w8n;
    }
    __syncthreads();

    // ---- phase 2: all taps from LDS, lane-contiguous b128 reads ----
    float* orow = out + (size_t)(b * H + y) * (W * CS) + x0 * CS;

    #pragma unroll
    for (int it = 0; it < 3; ++it) {
        int item = it * TPB + t;
        int p = item / 6;
        int q = item - p * 6;
        int qoff = q << 2;                 // 0,4,8,12,16,20

        const float4 pwA = *(const float4*)&s_w[p * 12 + 0];
        const float4 pwB = *(const float4*)&s_w[p * 12 + 4];
        const float  pw8 = s_w[p * 12 + 8];

        const float* base0 = &s_src[(0 * SLOTS + p) * STRIDE + qoff];
        const float* base1 = &s_src[(1 * SLOTS + p) * STRIDE + qoff];
        const float* base2 = &s_src[(2 * SLOTS + p) * STRIDE + qoff];

        float4 acc = {0.f, 0.f, 0.f, 0.f};
        fma4(acc, *(const float4*)(base0             ), pwA.x);  // row0, xm
        fma4(acc, *(const float4*)(base0 +     STRIDE), pwA.y);  // row0, x
        fma4(acc, *(const float4*)(base0 + 2 * STRIDE), pwA.z);  // row0, xp
        fma4(acc, *(const float4*)(base1             ), pwA.w);
        fma4(acc, *(const float4*)(base1 +     STRIDE), pwB.x);
        fma4(acc, *(const float4*)(base1 + 2 * STRIDE), pwB.y);
        fma4(acc, *(const float4*)(base2             ), pwB.z);
        fma4(acc, *(const float4*)(base2 +     STRIDE), pwB.w);
        fma4(acc, *(const float4*)(base2 + 2 * STRIDE), pw8);

        float* op = orow + p * CS + qoff;
        if (q < 5) *(float4*)op = acc;     // ch qoff..qoff+3
        else       *op = acc.x;            // ch 20 only
    }
}

extern "C" void kernel_launch(void* const* d_in, const int* in_sizes, int n_in,
                              void* d_out, int out_size, void* d_ws, size_t ws_size,
                              hipStream_t stream) {
    const float* src = (const float*)d_in[0];
    const float* im  = (const float*)d_in[1];
    float* out = (float*)d_out;
    dim3 grid((W / P) * H * BATCH, 1, 1);   // 4096 blocks, swizzle-decoded in-kernel
    jbu_kernel<<<grid, TPB, 0, stream>>>(src, im, out);
}

// Round 7
// 104.898 us; speedup vs baseline: 1.4567x; 1.4567x over previous
//
#include <hip/hip_runtime.h>

#define BATCH 2
#define H 512
#define W 512
#define CS 21
#define CI 3
#define P 128                   // pixels per block (x)
#define R 4                     // output rows per block (vertical run)
#define TPB 256
#define GROWS (R + 2)           // 6 tap rows
#define GSL (P + 2)             // 130 guide slots incl. halo
#define GSZ (GROWS * GSL * CI)  // 2340 guide floats

__device__ __forceinline__ void fma4(float4& a, const float4 v, const float w) {
    a.x = fmaf(v.x, w, a.x);
    a.y = fmaf(v.y, w, a.y);
    a.z = fmaf(v.z, w, a.z);
    a.w = fmaf(v.w, w, a.w);
}

// No src staging in LDS (R4/R5 barrier-serialization lesson). Each item owns
// a vertical run of 4 output rows for one (px, chunk): 18 tap loads feed 36
// fma4 with no barrier in between; y-overlap gives 2x register reuse while
// keeping R2's lane-contiguous global coalescing.
__global__ __launch_bounds__(TPB, 4) void jbu_kernel(
    const float* __restrict__ src, const float* __restrict__ im,
    float* __restrict__ out)
{
    __shared__ float s_g[GSZ];                    // 9,360 B guide tile
    __shared__ __align__(16) float s_w[R * P * 12];  // 24,576 B weights

    const int t = threadIdx.x;

    // XCD swizzle: XCD (f&7) owns a contiguous 64-output-row band.
    const int f      = blockIdx.x;        // 0..1023
    const int xcd    = f & 7;
    const int g      = f >> 3;            // 0..127
    const int rowgrp = (xcd << 4) | (g & 15);   // 0..127
    const int rem    = g >> 4;            // 0..7
    const int x0     = (rem & 3) << 7;    // segment * 128
    const int b      = rem >> 2;
    const int y0     = rowgrp << 2;       // output rows y0..y0+3

    int ty[GROWS];                        // tap rows y0-1 .. y0+4, reflected
    #pragma unroll
    for (int rr = 0; rr < GROWS; ++rr) {
        int v = y0 - 1 + rr;
        ty[rr] = (v < 0) ? 1 : ((v >= H) ? 2 * H - 2 - v : v);
    }

    // ---- stage guide tile ----
    const float* imb = im + (size_t)b * (H * W * CI);
    for (int i = t; i < GSZ; i += TPB) {
        int rr   = i / (GSL * CI);
        int remi = i - rr * (GSL * CI);
        int slot = remi / CI;
        int ch   = remi - slot * CI;
        int gx   = x0 + slot - 1;
        gx = (gx < 0) ? 1 : ((gx >= W) ? W - 2 : gx);
        s_g[i] = imb[(ty[rr] * W + gx) * CI + ch];
    }
    __syncthreads();

    // ---- weights: R*P = 512 sets, 2 per thread, normalized ----
    {
        const float w1k[9] = {0.36787944f, 0.60653066f, 0.36787944f,
                              0.60653066f, 1.0f,        0.60653066f,
                              0.36787944f, 0.60653066f, 0.36787944f};
        #pragma unroll
        for (int ii = 0; ii < (R * P) / TPB; ++ii) {
            int idx = ii * TPB + t;       // 0..511
            int r   = idx >> 7;           // 0..3   (idx / P)
            int px  = idx & (P - 1);
            int cb  = ((r + 1) * GSL + px + 1) * CI;
            float c0 = s_g[cb + 0], c1 = s_g[cb + 1], c2 = s_g[cb + 2];
            float wv[9];
            float den = 0.f;
            #pragma unroll
            for (int k = 0; k < 9; ++k) {
                int dy = k / 3, dx = k % 3;
                int ib = ((r + dy) * GSL + px + dx) * CI;
                float d0 = s_g[ib + 0] - c0;
                float d1 = s_g[ib + 1] - c1;
                float d2 = s_g[ib + 2] - c2;
                float w = __expf(-8.0f * (d0 * d0 + d1 * d1 + d2 * d2)) * w1k[k];
                wv[k] = w;
                den += w;
            }
            float inv = 1.0f / den;
            float* wd = &s_w[idx * 12];
            *(float4*)(wd + 0) = make_float4(wv[0] * inv, wv[1] * inv, wv[2] * inv, wv[3] * inv);
            *(float4*)(wd + 4) = make_float4(wv[4] * inv, wv[5] * inv, wv[6] * inv, wv[7] * inv);
            wd[8] = wv[8] * inv;
        }
    }
    __syncthreads();

    // ---- phase 2: vertical-run taps from global, weights from LDS ----
    const size_t rs = (size_t)W * CS;
    const float* sb = src + (size_t)b * H * rs;
    const float* srow[GROWS];
    #pragma unroll
    for (int rr = 0; rr < GROWS; ++rr)
        srow[rr] = sb + (size_t)ty[rr] * rs + (size_t)x0 * CS;
    float* ob = out + ((size_t)(b * H + y0)) * rs + (size_t)x0 * CS;

    #pragma unroll
    for (int it = 0; it < (P * 6) / TPB; ++it) {   // 3 iterations
        int item = it * TPB + t;
        int px = item / 6;
        int q  = item - px * 6;
        int coff = (q == 5) ? 17 : (q << 2);
        int x  = x0 + px;
        int xm = (x == 0)     ? 1     : x - 1;
        int xp = (x == W - 1) ? W - 2 : x + 1;
        int om = (xm - x0) * CS + coff;            // may be negative: valid in-row
        int oc = px * CS + coff;
        int op = (xp - x0) * CS + coff;

        float4 v[GROWS][3];
        #pragma unroll
        for (int rr = 0; rr < GROWS; ++rr) {
            v[rr][0] = *(const float4*)(srow[rr] + om);
            v[rr][1] = *(const float4*)(srow[rr] + oc);
            v[rr][2] = *(const float4*)(srow[rr] + op);
        }

        #pragma unroll
        for (int j = 0; j < R; ++j) {
            const float* wd = &s_w[(((j << 7) + px)) * 12];
            float4 wA = *(const float4*)(wd + 0);
            float4 wB = *(const float4*)(wd + 4);
            float  w8 = wd[8];
            float4 acc = {0.f, 0.f, 0.f, 0.f};
            fma4(acc, v[j + 0][0], wA.x);
            fma4(acc, v[j + 0][1], wA.y);
            fma4(acc, v[j + 0][2], wA.z);
            fma4(acc, v[j + 1][0], wA.w);
            fma4(acc, v[j + 1][1], wB.x);
            fma4(acc, v[j + 1][2], wB.y);
            fma4(acc, v[j + 2][0], wB.z);
            fma4(acc, v[j + 2][1], wB.w);
            fma4(acc, v[j + 2][2], w8);
            *(float4*)(ob + (size_t)j * rs + oc) = acc;
        }
    }
}

extern "C" void kernel_launch(void* const* d_in, const int* in_sizes, int n_in,
                              void* d_out, int out_size, void* d_ws, size_t ws_size,
                              hipStream_t stream) {
    const float* src = (const float*)d_in[0];
    const float* im  = (const float*)d_in[1];
    float* out = (float*)d_out;
    dim3 grid((W / P) * (H / R) * BATCH, 1, 1);   // 1024 blocks = 4/CU
    jbu_kernel<<<grid, TPB, 0, stream>>>(src, im, out);
}